// Round 4
// baseline (205.903 us; speedup 1.0000x reference)
//
#include <hip/hip_runtime.h>

// pred/target: (B=2, C=1, H=192, W=192, D=192) fp32, D contiguous.
// 5x5x5 box mean (zero pad), ncc = cross^2/(vi*vj+1e-5), loss = -mean(ncc).
#define HH 192
#define WW 192
#define DD 192
#define BB 2
#define TX 16            // d-tile (one output per thread along d)
#define WOUT 32          // w-tile (TWO outputs per thread along w)
#define HCHUNK 28        // h-slab; 7 slabs cover 196 (last clamped)
#define NSLAB 7
#define RY 36            // staged w-rows = WOUT + 4
#define RPX 10           // float2-pairs along d (20 floats = 16 + 4 halo)
#define NSTAGE (RY * RPX)     // 360 staging cells
#define SLICES (HCHUNK + 4)   // 32 h iterations

__global__ __launch_bounds__(256, 4)
void lncc_fused_kernel(const float* __restrict__ pred,
                       const float* __restrict__ targ,
                       double* __restrict__ acc_out) {
    // Raw slice, interleaved (p0,t0,p1,t1) per d-pair; double-buffered.
    // Row stride 10 float4 = 40 floats (the measured-good R2 layout).
    __shared__ float4 sPT[2][RY][RPX];
    // d-summed products, TRANSPOSED [d-cell][w-row], padded strides:
    // sR4 stride 37 cells (148 floats), sRe stride 39 floats -> 8 lanes per
    // 4-bank group on both the d-phase writes and the w-phase reads.
    __shared__ float4 sR4[TX][RY + 1];
    __shared__ float  sRe[TX][RY + 3];
    __shared__ float  wpart[4];

    const int tx = threadIdx.x;          // d cell
    const int ty = threadIdx.y;          // w group (2 outputs)
    const int tid = ty * TX + tx;

    const int d0 = blockIdx.x * TX;
    const int w0 = blockIdx.y * WOUT;
    const int bz = blockIdx.z;
    const int b  = bz / NSLAB;
    const int h0 = (bz - b * NSLAB) * HCHUNK;
    const long long base = (long long)b * ((long long)HH * WW * DD);

    // ---- staging map: cell p -> (row p/10, pair p%10); items tid and tid+256
    const int s0y = tid / RPX, s0x = tid - s0y * RPX;
    const int s1y = (tid + 256) / RPX, s1x = (tid + 256) - s1y * RPX;
    const int sw0 = w0 - 2 + s0y, sd0 = d0 - 2 + 2 * s0x;
    const int sw1 = w0 - 2 + s1y, sd1 = d0 - 2 + 2 * s1x;
    const bool s0ok = ((unsigned)sw0 < (unsigned)WW) & ((unsigned)sd0 < (unsigned)DD);
    const bool s1ok = (tid < NSTAGE - 256) &
                      ((unsigned)sw1 < (unsigned)WW) & ((unsigned)sd1 < (unsigned)DD);
    const int s0off = sw0 * DD + sd0;
    const int s1off = sw1 * DD + sd1;

    // ---- d-phase map: item p -> (row p/8, paircol p%8); items tid and tid+256
    const int d0y = tid >> 3, d0x = tid & 7;          // rows 0..31
    const int d1y = 32 + (tid >> 3), d1x = tid & 7;   // rows 32..35 (tid<32)

    auto load_slice = [&](int h, float2& pa, float2& ta, float2& pb, float2& tb) {
        pa = ta = pb = tb = make_float2(0.f, 0.f);
        if ((unsigned)h < (unsigned)HH) {
            const long long rowoff = base + (long long)h * (WW * DD);
            if (s0ok) {
                pa = *(const float2*)(pred + rowoff + s0off);
                ta = *(const float2*)(targ + rowoff + s0off);
            }
            if (s1ok) {
                pb = *(const float2*)(pred + rowoff + s1off);
                tb = *(const float2*)(targ + rowoff + s1off);
            }
        }
    };
    auto store_slice = [&](int buf, float2 pa, float2 ta, float2 pb, float2 tb) {
        sPT[buf][s0y][s0x] = make_float4(pa.x, ta.x, pa.y, ta.y);
        if (tid < NSTAGE - 256)
            sPT[buf][s1y][s1x] = make_float4(pb.x, tb.x, pb.y, tb.y);
    };
    auto dphase = [&](int buf, int yy, int xh) {
        const float4 c0 = sPT[buf][yy][xh];
        const float4 c1 = sPT[buf][yy][xh + 1];
        const float4 c2 = sPT[buf][yy][xh + 2];
        const float p0 = c0.x, q0 = c0.y, p1 = c0.z, q1 = c0.w;
        const float p2 = c1.x, q2 = c1.y, p3 = c1.z, q3 = c1.w;
        const float p4 = c2.x, q4 = c2.y, p5 = c2.z, q5 = c2.w;
        const float a0 = p0+p1+p2+p3+p4;
        const float a1 = q0+q1+q2+q3+q4;
        const float a2 = p0*p0+p1*p1+p2*p2+p3*p3+p4*p4;
        const float a3 = q0*q0+q1*q1+q2*q2+q3*q3+q4*q4;
        const float a4 = p0*q0+p1*q1+p2*q2+p3*q3+p4*q4;
        const float b0 = p1+p2+p3+p4+p5;
        const float b1 = q1+q2+q3+q4+q5;
        const float b2 = p1*p1+p2*p2+p3*p3+p4*p4+p5*p5;
        const float b3 = q1*q1+q2*q2+q3*q3+q4*q4+q5*q5;
        const float b4 = p1*q1+p2*q2+p3*q3+p4*q4+p5*q5;
        sR4[2*xh    ][yy] = make_float4(a0, a1, a2, a3);
        sR4[2*xh + 1][yy] = make_float4(b0, b1, b2, b3);
        sRe[2*xh    ][yy] = a4;
        sRe[2*xh + 1][yy] = b4;
    };

    // h rings for the two output columns (w = w0+2ty, w0+2ty+1), + running sums
    float rA[5][5], rB[5][5], sumA[5], sumB[5];
#pragma unroll
    for (int q = 0; q < 5; ++q) {
        sumA[q] = sumB[q] = 0.f;
#pragma unroll
        for (int i = 0; i < 5; ++i) { rA[q][i] = 0.f; rB[q][i] = 0.f; }
    }
    float acc = 0.0f;

    // preload + store slice 0
    {
        float2 pa, ta, pb, tb;
        load_slice(h0 - 2, pa, ta, pb, tb);
        store_slice(0, pa, ta, pb, tb);
    }
    __syncthreads();

    for (int it = 0; it < SLICES; ++it) {
        const int buf = it & 1;

        // prefetch next slice into registers (overlaps with d-phase LDS work)
        float2 npa, nta, npb, ntb;
        const bool more = (it + 1 < SLICES);
        if (more) load_slice(h0 - 1 + it, npa, nta, npb, ntb);

        // ---- d-phase ----
        dphase(buf, d0y, d0x);
        if (tid < 32) dphase(buf, d1y, d1x);
        __syncthreads();

        // ---- w-phase: 6 rows serve 2 outputs (sliding 5-window) ----
        float q0[6], q1[6], q2[6], q3[6], q4[6];
#pragma unroll
        for (int j = 0; j < 6; ++j) {
            const float4 v = sR4[tx][2 * ty + j];
            q0[j] = v.x; q1[j] = v.y; q2[j] = v.z; q3[j] = v.w;
            q4[j] = sRe[tx][2 * ty + j];
        }
        float An[5], Bn[5];
        An[0] = q0[0]+q0[1]+q0[2]+q0[3]+q0[4];  Bn[0] = An[0] + q0[5] - q0[0];
        An[1] = q1[0]+q1[1]+q1[2]+q1[3]+q1[4];  Bn[1] = An[1] + q1[5] - q1[0];
        An[2] = q2[0]+q2[1]+q2[2]+q2[3]+q2[4];  Bn[2] = An[2] + q2[5] - q2[0];
        An[3] = q3[0]+q3[1]+q3[2]+q3[3]+q3[4];  Bn[3] = An[3] + q3[5] - q3[0];
        An[4] = q4[0]+q4[1]+q4[2]+q4[3]+q4[4];  Bn[4] = An[4] + q4[5] - q4[0];

        // ring push with running h-sums
#pragma unroll
        for (int q = 0; q < 5; ++q) {
            sumA[q] += An[q] - rA[q][0];
            sumB[q] += Bn[q] - rB[q][0];
#pragma unroll
            for (int i = 0; i < 4; ++i) { rA[q][i] = rA[q][i+1]; rB[q][i] = rB[q][i+1]; }
            rA[q][4] = An[q];
            rB[q][4] = Bn[q];
        }

        // ---- emit the two voxels at (hout, w0+2ty(+1), d0+tx) ----
        const int hout = h0 + it - 4;
        if (it >= 4 && hout < HH) {
            const float inv = 1.0f / 125.0f;
            {
                const float uI = sumA[0]*inv, uJ = sumA[1]*inv;
                const float I2 = sumA[2]*inv, J2 = sumA[3]*inv, IJ = sumA[4]*inv;
                const float cross = IJ - uI*uJ, vi = I2 - uI*uI, vj = J2 - uJ*uJ;
                acc += (cross*cross) * __builtin_amdgcn_rcpf(vi*vj + 1e-5f);
            }
            {
                const float uI = sumB[0]*inv, uJ = sumB[1]*inv;
                const float I2 = sumB[2]*inv, J2 = sumB[3]*inv, IJ = sumB[4]*inv;
                const float cross = IJ - uI*uJ, vi = I2 - uI*uI, vj = J2 - uJ*uJ;
                acc += (cross*cross) * __builtin_amdgcn_rcpf(vi*vj + 1e-5f);
            }
        }

        // ---- store next slice (consumes the prefetch) ----
        if (more) store_slice(buf ^ 1, npa, nta, npb, ntb);
        __syncthreads();
    }

    // ---- block reduction, one double atomic per block ----
#pragma unroll
    for (int off = 32; off > 0; off >>= 1) acc += __shfl_down(acc, off, 64);
    const int wid = tid >> 6, lane = tid & 63;
    if (lane == 0) wpart[wid] = acc;
    __syncthreads();
    if (tid == 0)
        atomicAdd(acc_out, (double)(wpart[0] + wpart[1] + wpart[2] + wpart[3]));
}

__global__ void lncc_finalize_kernel(const double* __restrict__ acc,
                                     float* __restrict__ out) {
    const double n = (double)BB * HH * WW * DD;
    out[0] = (float)(-acc[0] / n);
}

extern "C" void kernel_launch(void* const* d_in, const int* in_sizes, int n_in,
                              void* d_out, int out_size, void* d_ws, size_t ws_size,
                              hipStream_t stream) {
    const float* pred = (const float*)d_in[0];
    const float* targ = (const float*)d_in[1];
    float* out = (float*)d_out;
    double* acc = (double*)d_ws;

    hipMemsetAsync(d_ws, 0, sizeof(double), stream);

    dim3 grid(DD / TX, WW / WOUT, BB * NSLAB);   // 12 x 6 x 14 = 1008 blocks
    dim3 block(TX, TX, 1);                       // 256 threads
    lncc_fused_kernel<<<grid, block, 0, stream>>>(pred, targ, acc);
    lncc_finalize_kernel<<<1, 1, 0, stream>>>(acc, out);
}

// Round 5
// 205.247 us; speedup vs baseline: 1.0032x; 1.0032x over previous
//
#include <hip/hip_runtime.h>

// pred/target: (B=2, C=1, H=192, W=192, D=192) fp32, D contiguous.
// 5x5x5 box mean (zero pad), ncc = cross^2/(vi*vj+1e-5), loss = -mean(ncc).
#define HH 192
#define WW 192
#define DD 192
#define BB 2
#define HCHUNK 40
#define NSLAB 5              // 5*40 = 200 >= 192, grid 12*12*10 = 1440 blocks
#define SLICES (HCHUNK + 4)  // 44, even -> unroll-2 folds buf parity

// LDS layout (byte offsets). Raw slice: 2 bufs x 20 rows x 10 float4 cells.
// Cell = (p[2k], t[2k], p[2k+1], t[2k+1]).
#define PT_BUF   3200
#define PT_ROW   160
// d-summed streams: S = row-pair sums, O = raw odd rows, E = raw even rows.
// Quad part (sI,sJ,sII,sJJ) stride 17 float4; IJ part stride 16 floats.
#define SQ_OFF   6400        // 10 * 272
#define OQ_OFF   9120
#define EQ_OFF   11840
#define SIJ_OFF  14560       // 10 * 64
#define OIJ_OFF  15200
#define EIJ_OFF  15840
#define LDS_BYTES 16480
#define QROW 272
#define IJROW 64

__global__ __launch_bounds__(256, 6)
void lncc_fused_kernel(const float* __restrict__ pred,
                       const float* __restrict__ targ,
                       double* __restrict__ acc_out) {
    __shared__ alignas(16) char lds[LDS_BYTES];
    __shared__ float wpart[4];

    const int tx = threadIdx.x, ty = threadIdx.y;
    const int tid = ty * 16 + tx;

    const int d0 = blockIdx.x * 16;
    const int w0 = blockIdx.y * 16;
    const int bz = blockIdx.z;
    const int b  = bz / NSLAB;
    const int h0 = (bz - b * NSLAB) * HCHUNK;
    const int base = b * (HH * WW * DD);

    // ---- stage map: 200 items, one float2-pair (p,t) each ----
    const int syy = tid / 10;
    const int spx = tid - syy * 10;
    const int sw  = w0 - 2 + syy;
    const int sd  = d0 - 2 + 2 * spx;
    const bool s_ok = (tid < 200) & ((unsigned)sw < (unsigned)WW) & ((unsigned)sd < (unsigned)DD);
    const int spos = base + sw * DD + sd;
    char* const stW = lds + (syy * PT_ROW + spx * 16);

    // ---- d-phase map: 80 threads, each one row-pair x one d-pair ----
    const bool d_act = (tid < 80);
    const int dk = tid >> 3, dx = tid & 7;
    const char* const dR  = lds + (2 * dk * PT_ROW + dx * 16);
    char* const dWq  = lds + (SQ_OFF  + dk * QROW  + 2 * dx * 16);
    char* const dWij = lds + (SIJ_OFF + dk * IJROW + 2 * dx * 4);

    // ---- w-phase addrs (hoisted; 3 quad + 3 IJ reads per slice) ----
    // even ty=2m:  S[m]   + S[m+1] + E[m+2]
    // odd  ty=2m+1: O[m]  + S[m+1] + S[m+2]
    const int m = ty >> 1;
    const int osel = ty & 1;
    const char* const aQ1 = lds + (SQ_OFF + m * QROW + tx * 16 + (osel ? (OQ_OFF - SQ_OFF) : 0));
    const char* const aQ2 = lds + (SQ_OFF + (m + 1) * QROW + tx * 16);
    const char* const aQ3 = lds + (SQ_OFF + (m + 2) * QROW + tx * 16 + (osel ? 0 : (EQ_OFF - SQ_OFF)));
    const char* const aI1 = lds + (SIJ_OFF + m * IJROW + tx * 4 + (osel ? (OIJ_OFF - SIJ_OFF) : 0));
    const char* const aI2 = lds + (SIJ_OFF + (m + 1) * IJROW + tx * 4);
    const char* const aI3 = lds + (SIJ_OFF + (m + 2) * IJROW + tx * 4 + (osel ? 0 : (EIJ_OFF - SIJ_OFF)));

    // h ring (outgoing values) + running h-sums
    float ring[5][5];
    float hs0 = 0.f, hs1 = 0.f, hs2 = 0.f, hs3 = 0.f, hs4 = 0.f;
#pragma unroll
    for (int q = 0; q < 5; ++q)
#pragma unroll
        for (int i = 0; i < 5; ++i) ring[q][i] = 0.f;
    float acc = 0.f;

#pragma unroll 2
    for (int it = 0; it < SLICES; ++it) {
        const int buf = it & 1;
        const int h = h0 - 2 + it;

        // ---- stage ----
        if (tid < 200) {
            float2 pv = make_float2(0.f, 0.f), tv = make_float2(0.f, 0.f);
            if (s_ok & ((unsigned)h < (unsigned)HH)) {
                const int idx = spos + h * (WW * DD);
                pv = *(const float2*)(pred + idx);
                tv = *(const float2*)(targ + idx);
            }
            *(float4*)(stW + buf * PT_BUF) = make_float4(pv.x, tv.x, pv.y, tv.y);
        }
        __syncthreads();

        // ---- d-phase: rows 2k,2k+1; outputs d=2dx,2dx+1; 3 streams ----
        if (d_act) {
            const char* R = dR + buf * PT_BUF;
            const float4 c0 = *(const float4*)(R);
            const float4 c1 = *(const float4*)(R + 16);
            const float4 c2 = *(const float4*)(R + 32);
            // row 2k (even)
            float ea0, ea1, ea2, ea3, ea4, eb0, eb1, eb2, eb3, eb4;
            {
                const float p0 = c0.x, q0 = c0.y, p1 = c0.z, q1 = c0.w;
                const float p2 = c1.x, q2 = c1.y, p3 = c1.z, q3 = c1.w;
                const float p4 = c2.x, q4 = c2.y, p5 = c2.z, q5 = c2.w;
                ea0 = p0 + p1 + p2 + p3 + p4;              eb0 = ea0 - p0 + p5;
                ea1 = q0 + q1 + q2 + q3 + q4;              eb1 = ea1 - q0 + q5;
                const float pp0 = p0 * p0, pp5 = p5 * p5;
                const float qq0 = q0 * q0, qq5 = q5 * q5;
                const float pq0 = p0 * q0, pq5 = p5 * q5;
                ea2 = pp0 + p1*p1 + p2*p2 + p3*p3 + p4*p4; eb2 = ea2 - pp0 + pp5;
                ea3 = qq0 + q1*q1 + q2*q2 + q3*q3 + q4*q4; eb3 = ea3 - qq0 + qq5;
                ea4 = pq0 + p1*q1 + p2*q2 + p3*q3 + p4*q4; eb4 = ea4 - pq0 + pq5;
            }
            // write E stream (raw even row)
            *(float4*)(dWq + (EQ_OFF - SQ_OFF))      = make_float4(ea0, ea1, ea2, ea3);
            *(float4*)(dWq + (EQ_OFF - SQ_OFF) + 16) = make_float4(eb0, eb1, eb2, eb3);
            *(float2*)(dWij + (EIJ_OFF - SIJ_OFF))   = make_float2(ea4, eb4);
            // row 2k+1 (odd)
            const float4 c3 = *(const float4*)(R + PT_ROW);
            const float4 c4 = *(const float4*)(R + PT_ROW + 16);
            const float4 c5 = *(const float4*)(R + PT_ROW + 32);
            float oa0, oa1, oa2, oa3, oa4, ob0, ob1, ob2, ob3, ob4;
            {
                const float p0 = c3.x, q0 = c3.y, p1 = c3.z, q1 = c3.w;
                const float p2 = c4.x, q2 = c4.y, p3 = c4.z, q3 = c4.w;
                const float p4 = c5.x, q4 = c5.y, p5 = c5.z, q5 = c5.w;
                oa0 = p0 + p1 + p2 + p3 + p4;              ob0 = oa0 - p0 + p5;
                oa1 = q0 + q1 + q2 + q3 + q4;              ob1 = oa1 - q0 + q5;
                const float pp0 = p0 * p0, pp5 = p5 * p5;
                const float qq0 = q0 * q0, qq5 = q5 * q5;
                const float pq0 = p0 * q0, pq5 = p5 * q5;
                oa2 = pp0 + p1*p1 + p2*p2 + p3*p3 + p4*p4; ob2 = oa2 - pp0 + pp5;
                oa3 = qq0 + q1*q1 + q2*q2 + q3*q3 + q4*q4; ob3 = oa3 - qq0 + qq5;
                oa4 = pq0 + p1*q1 + p2*q2 + p3*q3 + p4*q4; ob4 = oa4 - pq0 + pq5;
            }
            // write O stream (raw odd row)
            *(float4*)(dWq + (OQ_OFF - SQ_OFF))      = make_float4(oa0, oa1, oa2, oa3);
            *(float4*)(dWq + (OQ_OFF - SQ_OFF) + 16) = make_float4(ob0, ob1, ob2, ob3);
            *(float2*)(dWij + (OIJ_OFF - SIJ_OFF))   = make_float2(oa4, ob4);
            // write S stream (pair sum)
            *(float4*)(dWq)      = make_float4(ea0 + oa0, ea1 + oa1, ea2 + oa2, ea3 + oa3);
            *(float4*)(dWq + 16) = make_float4(eb0 + ob0, eb1 + ob1, eb2 + ob2, eb3 + ob3);
            *(float2*)(dWij)     = make_float2(ea4 + oa4, eb4 + ob4);
        }
        __syncthreads();

        // ---- w-phase: 3 quad + 3 scalar reads -> w-sum done ----
        const float4 Q1 = *(const float4*)aQ1;
        const float4 Q2 = *(const float4*)aQ2;
        const float4 Q3 = *(const float4*)aQ3;
        const float An0 = Q1.x + Q2.x + Q3.x;
        const float An1 = Q1.y + Q2.y + Q3.y;
        const float An2 = Q1.z + Q2.z + Q3.z;
        const float An3 = Q1.w + Q2.w + Q3.w;
        const float An4 = *(const float*)aI1 + *(const float*)aI2 + *(const float*)aI3;

        // running h-sums + ring push
        hs0 += An0 - ring[0][0];
        hs1 += An1 - ring[1][0];
        hs2 += An2 - ring[2][0];
        hs3 += An3 - ring[3][0];
        hs4 += An4 - ring[4][0];
#pragma unroll
        for (int q = 0; q < 5; ++q)
#pragma unroll
            for (int i = 0; i < 4; ++i) ring[q][i] = ring[q][i + 1];
        ring[0][4] = An0; ring[1][4] = An1; ring[2][4] = An2;
        ring[3][4] = An3; ring[4][4] = An4;

        // ---- emit voxel (h0+it-4, w0+ty, d0+tx) ----
        if (it >= 4) {
            const int hout = h0 + it - 4;
            if (hout < HH) {
                const float inv = 1.0f / 125.0f;
                const float uI = hs0 * inv, uJ = hs1 * inv;
                const float I2 = hs2 * inv, J2 = hs3 * inv, IJ = hs4 * inv;
                const float cross = IJ - uI * uJ;
                const float vi = I2 - uI * uI;
                const float vj = J2 - uJ * uJ;
                acc += (cross * cross) * __builtin_amdgcn_rcpf(vi * vj + 1e-5f);
            }
        }
        // no end barrier: next iteration's first sync orders w-reads vs d-writes
    }

    // ---- block reduction, one double atomic per block ----
#pragma unroll
    for (int off = 32; off > 0; off >>= 1) acc += __shfl_down(acc, off, 64);
    const int wid = tid >> 6, lane = tid & 63;
    if (lane == 0) wpart[wid] = acc;
    __syncthreads();
    if (tid == 0)
        atomicAdd(acc_out, (double)(wpart[0] + wpart[1] + wpart[2] + wpart[3]));
}

__global__ void lncc_finalize_kernel(const double* __restrict__ acc,
                                     float* __restrict__ out) {
    const double n = (double)BB * HH * WW * DD;
    out[0] = (float)(-acc[0] / n);
}

extern "C" void kernel_launch(void* const* d_in, const int* in_sizes, int n_in,
                              void* d_out, int out_size, void* d_ws, size_t ws_size,
                              hipStream_t stream) {
    const float* pred = (const float*)d_in[0];
    const float* targ = (const float*)d_in[1];
    float* out = (float*)d_out;
    double* acc = (double*)d_ws;

    hipMemsetAsync(d_ws, 0, sizeof(double), stream);

    dim3 grid(DD / 16, WW / 16, BB * NSLAB);   // 12 x 12 x 10 = 1440 blocks
    dim3 block(16, 16, 1);                     // 256 threads
    lncc_fused_kernel<<<grid, block, 0, stream>>>(pred, targ, acc);
    lncc_finalize_kernel<<<1, 1, 0, stream>>>(acc, out);
}